// Round 1
// baseline (1437.559 us; speedup 1.0000x reference)
//
#include <hip/hip_runtime.h>
#include <cstdint>
#include <cstddef>

typedef float v4f __attribute__((ext_vector_type(4)));

constexpr int N = 2048;
constexpr int T = 16;
constexpr int D = 16;
constexpr int H = 64;
constexpr size_t NPAIRS = (size_t)N * N; // 4194304

__device__ __forceinline__ float leaky(float x) { return fmaxf(0.2f * x, x); }
__device__ __forceinline__ float bcast(float v, int l) {
  return __int_as_float(__builtin_amdgcn_readlane(__float_as_int(v), l));
}
__device__ __forceinline__ float sigmoidf_(float x) { return 1.0f / (1.0f + __expf(-x)); }
__device__ __forceinline__ float tanhf_(float x) {
  float e = __expf(2.0f * x);
  return (e - 1.0f) / (e + 1.0f);
}

// ---------------------------------------------------------------------------
// K1: LSTM. 4 samples per block, 256 threads. Thread g owns gate-row g
// (W_hh row in 64 VGPRs, W_ih row in 16 VGPRs). h broadcast across the wave
// via v_readlane (no LDS-pipe pressure in the inner product).
// ---------------------------------------------------------------------------
__global__ __launch_bounds__(256, 2)
void k_lstm(const float* __restrict__ x, const float* __restrict__ W_ih,
            const float* __restrict__ W_hh, const float* __restrict__ b_ih,
            const float* __restrict__ b_hh, float* __restrict__ sem)
{
  const int tid = threadIdx.x;
  const int g = tid;                 // gate-unit index 0..255 (i,f,g,o x 64)
  const int nbase = blockIdx.x * 4;  // 4 samples per block
  const int lane = tid & 63;
  const int s_u = tid >> 6, h_u = tid & 63;

  __shared__ float h_all[4][64];
  __shared__ float pre_s[4][256];

  float whh[64];
  {
    const v4f* wrp = (const v4f*)(W_hh + (size_t)g * 64);
    #pragma unroll
    for (int k4 = 0; k4 < 16; ++k4) {
      v4f v = wrp[k4];
      whh[4*k4+0] = v.x; whh[4*k4+1] = v.y; whh[4*k4+2] = v.z; whh[4*k4+3] = v.w;
    }
  }
  float wih[16];
  {
    const v4f* wip = (const v4f*)(W_ih + (size_t)g * 16);
    #pragma unroll
    for (int d4 = 0; d4 < 4; ++d4) {
      v4f v = wip[d4];
      wih[4*d4+0] = v.x; wih[4*d4+1] = v.y; wih[4*d4+2] = v.z; wih[4*d4+3] = v.w;
    }
  }
  const float bsum = b_ih[g] + b_hh[g];

  h_all[s_u][h_u] = 0.0f;
  float c = 0.0f;
  float hn = 0.0f;
  __syncthreads();

  #pragma unroll 1
  for (int t = 0; t < T; ++t) {
    float p[4], hv[4];
    #pragma unroll
    for (int s = 0; s < 4; ++s) { hv[s] = h_all[s][lane]; p[s] = bsum; }
    // input projection (x values are wave-uniform broadcasts, L1-hot)
    #pragma unroll
    for (int s = 0; s < 4; ++s) {
      const v4f* xp = (const v4f*)(x + ((size_t)(nbase + s) * T + t) * D);
      #pragma unroll
      for (int d4 = 0; d4 < 4; ++d4) {
        v4f xv = xp[d4];
        p[s] += wih[4*d4+0]*xv.x + wih[4*d4+1]*xv.y + wih[4*d4+2]*xv.z + wih[4*d4+3]*xv.w;
      }
    }
    // recurrent projection: h[k] broadcast via readlane (SGPR operand to FMA)
    #pragma unroll
    for (int k = 0; k < 64; ++k) {
      float w = whh[k];
      #pragma unroll
      for (int s = 0; s < 4; ++s) p[s] = fmaf(w, bcast(hv[s], k), p[s]);
    }
    #pragma unroll
    for (int s = 0; s < 4; ++s) pre_s[s][g] = p[s];
    __syncthreads();
    // update phase: thread (s_u, h_u)
    float gi = sigmoidf_(pre_s[s_u][h_u]);
    float gf = sigmoidf_(pre_s[s_u][64 + h_u]);
    float gg = tanhf_(pre_s[s_u][128 + h_u]);
    float go = sigmoidf_(pre_s[s_u][192 + h_u]);
    c = gf * c + gi * gg;
    hn = go * tanhf_(c);
    h_all[s_u][h_u] = hn;
    __syncthreads();
  }
  sem[(size_t)(nbase + s_u) * H + h_u] = hn;
}

// ---------------------------------------------------------------------------
// K1b: per-row stats from seq_emb: ht[i] = leaky(sem.w2+b2)+leaky(sem.w3+b3),
// sa[i] = sem.w4[0:64], sb[i] = sem.w4[64:128]. One wave per row.
// ---------------------------------------------------------------------------
__global__ __launch_bounds__(256, 4)
void k_rowstats(const float* __restrict__ sem, const float* __restrict__ w2,
                const float* __restrict__ b2, const float* __restrict__ w3,
                const float* __restrict__ b3, const float* __restrict__ w4,
                float* __restrict__ ht, float* __restrict__ sa, float* __restrict__ sb)
{
  int lane = threadIdx.x & 63;
  int i = blockIdx.x * 4 + (threadIdx.x >> 6);
  float se = sem[(size_t)i * H + lane];
  float d2  = se * w2[lane];
  float d3  = se * w3[lane];
  float d4a = se * w4[lane];
  float d4b = se * w4[64 + lane];
  #pragma unroll
  for (int m = 32; m >= 1; m >>= 1) {
    d2  += __shfl_xor(d2, m);
    d3  += __shfl_xor(d3, m);
    d4a += __shfl_xor(d4a, m);
    d4b += __shfl_xor(d4b, m);
  }
  if (lane == 0) {
    ht[i] = leaky(d2 + b2[0]) + leaky(d3 + b3[0]);
    sa[i] = d4a;
    sb[i] = d4b;
  }
}

// ---------------------------------------------------------------------------
// K2: the 1 GB streaming kernel. Each wave-iter reads 2 KB of relation
// (8 (i,j) pairs; 16 lanes x float4 per pair), dots with w1, leaky, adds
// rel_mask + ht[i], exp, stores e[i,j]. Nontemporal: relation/rel_mask are
// touched exactly once.
// ---------------------------------------------------------------------------
__global__ __launch_bounds__(256, 8)
void k_rel(const float* __restrict__ relation, const float* __restrict__ rel_mask,
           const float* __restrict__ w1, const float* __restrict__ b1,
           const float* __restrict__ ht, float* __restrict__ e_out)
{
  const int lane = threadIdx.x & 63;
  const int gw = (int)((blockIdx.x * blockDim.x + threadIdx.x) >> 6);
  const int p = lane >> 4;                       // pair subgroup 0..3
  const v4f w1c = ((const v4f*)w1)[lane & 15];   // w1 chunk for this lane
  const float b1v = b1[0];
  const size_t qstride = (size_t)((gridDim.x * blockDim.x) >> 6) * 8;
  for (size_t q = (size_t)gw * 8; q < NPAIRS; q += qstride) {
    const v4f* rp = (const v4f*)relation + q * 16 + lane;
    v4f ra = __builtin_nontemporal_load(rp);
    v4f rb = __builtin_nontemporal_load(rp + 64);
    float pa = ra.x*w1c.x + ra.y*w1c.y + ra.z*w1c.z + ra.w*w1c.w;
    float pb = rb.x*w1c.x + rb.y*w1c.y + rb.z*w1c.z + rb.w*w1c.w;
    pa += __shfl_xor(pa, 8); pa += __shfl_xor(pa, 4);
    pa += __shfl_xor(pa, 2); pa += __shfl_xor(pa, 1);
    pb += __shfl_xor(pb, 8); pb += __shfl_xor(pb, 4);
    pb += __shfl_xor(pb, 2); pb += __shfl_xor(pb, 1);
    const float hti = ht[q >> 11];
    float ma = __builtin_nontemporal_load(rel_mask + q + p);
    float mb = __builtin_nontemporal_load(rel_mask + q + 4 + p);
    float ea = __expf(ma + hti + leaky(pa + b1v));
    float eb = __expf(mb + hti + leaky(pb + b1v));
    if ((lane & 15) == 0) {
      e_out[q + p] = ea;
      e_out[q + 4 + p] = eb;
    }
  }
}

// ---------------------------------------------------------------------------
// K2b: column sums Z_j = sum_i e[i][j] (softmax denominators, no max-shift
// needed: logits bounded ~|7|). Partial per 64-row stripe + one atomic.
// ---------------------------------------------------------------------------
__global__ __launch_bounds__(256, 8)
void k_colsum(const float* __restrict__ e, float* __restrict__ Z)
{
  int j = blockIdx.x * 256 + threadIdx.x;
  int i0 = blockIdx.y * 64;
  float acc = 0.f;
  #pragma unroll 4
  for (int r = 0; r < 64; ++r) acc += e[(size_t)(i0 + r) * N + j];
  atomicAdd(&Z[j], acc);
}

// K2c: t_j = (sem[j].w4b) / Z_j
__global__ void k_tvec(const float* __restrict__ sb, const float* __restrict__ Z,
                       float* __restrict__ tv)
{
  int j = blockIdx.x * 256 + threadIdx.x;
  tv[j] = sb[j] / Z[j];
}

// ---------------------------------------------------------------------------
// K3: pred[i] = leaky(sa[i] + b4 + sum_j e[i][j] * t[j]). One wave per row,
// float4 coalesced reads of the e row.
// ---------------------------------------------------------------------------
__global__ __launch_bounds__(256, 8)
void k_final(const float* __restrict__ e, const float* __restrict__ tv,
             const float* __restrict__ sa, const float* __restrict__ b4,
             float* __restrict__ out)
{
  int lane = threadIdx.x & 63;
  int i = blockIdx.x * 4 + (threadIdx.x >> 6);
  const v4f* ep = (const v4f*)e + (size_t)i * (N / 4);
  const v4f* tp = (const v4f*)tv;
  float acc = 0.f;
  #pragma unroll
  for (int it = 0; it < N / 256; ++it) {
    v4f ev = ep[it * 64 + lane];
    v4f tw = tp[it * 64 + lane];
    acc += ev.x*tw.x + ev.y*tw.y + ev.z*tw.z + ev.w*tw.w;
  }
  #pragma unroll
  for (int m = 32; m >= 1; m >>= 1) acc += __shfl_xor(acc, m);
  if (lane == 0) {
    float v = acc + sa[i] + b4[0];
    out[i] = leaky(v);
  }
}

extern "C" void kernel_launch(void* const* d_in, const int* in_sizes, int n_in,
                              void* d_out, int out_size, void* d_ws, size_t ws_size,
                              hipStream_t stream) {
  (void)in_sizes; (void)n_in; (void)out_size; (void)ws_size;
  const float* x        = (const float*)d_in[0];
  const float* relation = (const float*)d_in[1];
  const float* rel_mask = (const float*)d_in[2];
  const float* W_ih     = (const float*)d_in[3];
  const float* W_hh     = (const float*)d_in[4];
  const float* b_ih     = (const float*)d_in[5];
  const float* b_hh     = (const float*)d_in[6];
  const float* w1       = (const float*)d_in[7];
  const float* b1       = (const float*)d_in[8];
  const float* w2       = (const float*)d_in[9];
  const float* b2       = (const float*)d_in[10];
  const float* w3       = (const float*)d_in[11];
  const float* b3       = (const float*)d_in[12];
  const float* w4       = (const float*)d_in[13];
  const float* b4       = (const float*)d_in[14];

  float* ws  = (float*)d_ws;
  float* e   = ws;                          // [N*N]           16.78 MB
  float* sem = e + NPAIRS;                  // [N*H]           0.5 MB
  float* ht  = sem + (size_t)N * H;         // [N]
  float* sa  = ht + N;                      // [N]
  float* sb  = sa + N;                      // [N]
  float* Z   = sb + N;                      // [N]
  float* tv  = Z + N;                       // [N]

  k_lstm<<<N / 4, 256, 0, stream>>>(x, W_ih, W_hh, b_ih, b_hh, sem);
  k_rowstats<<<N / 4, 256, 0, stream>>>(sem, w2, b2, w3, b3, w4, ht, sa, sb);
  k_rel<<<2048, 256, 0, stream>>>(relation, rel_mask, w1, b1, ht, e);
  (void)hipMemsetAsync(Z, 0, N * sizeof(float), stream);
  k_colsum<<<dim3(N / 256, 32), 256, 0, stream>>>(e, Z);
  k_tvec<<<N / 256, 256, 0, stream>>>(sb, Z, tv);
  k_final<<<N / 4, 256, 0, stream>>>(e, tv, sa, b4, (float*)d_out);
}